// Round 9
// baseline (467.821 us; speedup 1.0000x reference)
//
#include <hip/hip_runtime.h>
#include <hip/hip_bf16.h>

#define D_IN   256
#define D_HID  128
#define D_OUT_ 64
#define NGRAPH 16
#define BN_EPS 1e-5f

#define SCAN_TPB 256
#define SCAN_VPT 4            // 1024 elements per block

typedef __attribute__((ext_vector_type(8))) short short8;
typedef __attribute__((ext_vector_type(4))) float floatx4;

// ---------------- helpers ----------------
__device__ __forceinline__ unsigned short f2bf(float x) {   // RNE f32->bf16
    unsigned u = __float_as_uint(x);
    return (unsigned short)((u + 0x7fffu + ((u >> 16) & 1u)) >> 16);
}
__device__ __forceinline__ unsigned pack2bf(float lo, float hi) {
    return (unsigned)f2bf(lo) | ((unsigned)f2bf(hi) << 16);
}
__device__ __forceinline__ void bf2_decode(unsigned u, float& lo, float& hi) {
    lo = __uint_as_float(u << 16);
    hi = __uint_as_float(u & 0xffff0000u);
}
// acc[0..7] += wt * bf16x8(qv)
__device__ __forceinline__ void accum8(float* acc, uint4 qv, float wt) {
    float f0,f1,f2,f3,f4,f5,f6,f7;
    bf2_decode(qv.x, f0, f1); bf2_decode(qv.y, f2, f3);
    bf2_decode(qv.z, f4, f5); bf2_decode(qv.w, f6, f7);
    acc[0]=fmaf(f0,wt,acc[0]); acc[1]=fmaf(f1,wt,acc[1]);
    acc[2]=fmaf(f2,wt,acc[2]); acc[3]=fmaf(f3,wt,acc[3]);
    acc[4]=fmaf(f4,wt,acc[4]); acc[5]=fmaf(f5,wt,acc[5]);
    acc[6]=fmaf(f6,wt,acc[6]); acc[7]=fmaf(f7,wt,acc[7]);
}

// ---------------- CSR build ----------------
// rank[e] = arrival order of edge e within its dst row (atomicAdd return value).
// This makes the later scatter completely atomic-free.
__global__ void count_rank_kernel(const int* __restrict__ dst, int E,
                                  int* __restrict__ deg, int* __restrict__ rank) {
    int e = blockIdx.x * blockDim.x + threadIdx.x;
    if (e < E) rank[e] = atomicAdd(&deg[dst[e]], 1);
}

__global__ void dinv_kernel(const int* __restrict__ deg, int N, float* __restrict__ dinv) {
    int v = blockIdx.x * blockDim.x + threadIdx.x;
    if (v < N) dinv[v] = rsqrtf((float)(deg[v] + 1));   // +1 self-loop
}

__global__ void block_sum_kernel(const int* __restrict__ deg, int N, int* __restrict__ bsum) {
    __shared__ int red[SCAN_TPB];
    int t = threadIdx.x;
    int base = blockIdx.x * (SCAN_TPB * SCAN_VPT) + t;
    int s = 0;
    #pragma unroll
    for (int i = 0; i < SCAN_VPT; ++i) {
        int idx = base + i * SCAN_TPB;
        if (idx < N) s += deg[idx];
    }
    red[t] = s;
    __syncthreads();
    for (int off = SCAN_TPB / 2; off > 0; off >>= 1) {
        if (t < off) red[t] += red[t + off];
        __syncthreads();
    }
    if (t == 0) bsum[blockIdx.x] = red[0];
}

__global__ void scan_bsum_kernel(const int* __restrict__ bsum, int NB,
                                 int* __restrict__ bprefix,
                                 int* __restrict__ rowstart, int N, int E) {
    __shared__ int part[SCAN_TPB];
    int t = threadIdx.x;
    int s = (t < NB) ? bsum[t] : 0;
    part[t] = s;
    __syncthreads();
    for (int off = 1; off < SCAN_TPB; off <<= 1) {
        int x = (t >= off) ? part[t - off] : 0;
        __syncthreads();
        part[t] += x;
        __syncthreads();
    }
    if (t < NB) bprefix[t] = part[t] - s;   // exclusive prefix of block sums
    if (t == 0) rowstart[N] = E;            // total degree == E analytically
}

__global__ void local_scan_kernel(const int* __restrict__ deg, int N,
                                  const int* __restrict__ bprefix,
                                  int* __restrict__ rowstart) {
    __shared__ int part[SCAN_TPB];
    int t = threadIdx.x;
    int base = blockIdx.x * (SCAN_TPB * SCAN_VPT) + t * SCAN_VPT;
    int v[SCAN_VPT];
    int s = 0;
    #pragma unroll
    for (int i = 0; i < SCAN_VPT; ++i) {
        v[i] = (base + i < N) ? deg[base + i] : 0;
        s += v[i];
    }
    part[t] = s;
    __syncthreads();
    for (int off = 1; off < SCAN_TPB; off <<= 1) {   // inclusive Hillis-Steele
        int x = (t >= off) ? part[t - off] : 0;
        __syncthreads();
        part[t] += x;
        __syncthreads();
    }
    int excl = part[t] - s + bprefix[blockIdx.x];
    #pragma unroll
    for (int i = 0; i < SCAN_VPT; ++i) {
        if (base + i < N) rowstart[base + i] = excl;
        excl += v[i];
    }
}

// ---------------- weight prep: W[K][NOUT] f32 -> Wt[NOUT][K] bf16 ----------------
__global__ void wprep_kernel(const float* __restrict__ W, int K, int NOUT,
                             unsigned short* __restrict__ Wt) {
    int idx = blockIdx.x * blockDim.x + threadIdx.x;
    if (idx >= K * NOUT) return;
    int k = idx / NOUT, n = idx - k * NOUT;
    Wt[(size_t)n * K + k] = f2bf(W[idx]);
}

// ---------------- MFMA GEMM body: Cb[M][NOUT] bf16 = act(A)[M][K] @ Wt^T ----------
// FUSE: BN scale/shift computed per block from raw sums/sumsq into LDS.
// sched_barrier(0) after the load loop: force ALL A-loads issued before the
// first convert (r8 post-mortem: compiler serialized loads at VGPR=52).
// Layouts: A[m=lane&15][k=quad*8+j], B[k=quad*8+j][n=lane&15], C/D col=lane&15 row=quad*4+reg.
template<int K, int NOUT, int FUSE, int ABF16>
__device__ __forceinline__ void gemm_body(
        int bid, const void* __restrict__ Aptr, const unsigned short* __restrict__ Wt,
        unsigned short* __restrict__ Cb, int M,
        const float* __restrict__ sums, const float* __restrict__ sumsq,
        const float* __restrict__ gam, const float* __restrict__ bet, float invN) {
    constexpr int NT = NOUT / 16;
    constexpr int KS = K / 32;
    __shared__ float s_sc[FUSE ? K : 1];
    __shared__ float s_sh[FUSE ? K : 1];
    if (FUSE) {
        int t = threadIdx.x;
        if (t < K) {
            float mu  = sums[t] * invN;
            float var = sumsq[t] * invN - mu * mu;
            float sc  = gam[t] * rsqrtf(var + BN_EPS);
            s_sc[t] = sc;
            s_sh[t] = fmaf(-mu, sc, bet[t]);
        }
        __syncthreads();
    }
    int lane = threadIdx.x & 63;
    int wave = threadIdx.x >> 6;
    int col  = lane & 15;
    int quad = lane >> 4;
    int kq   = quad * 8;
    int row  = bid * 64 + wave * 16 + col;
    int rowc = min(row, M - 1);

    short8 afr[KS];
    if (ABF16) {
        const unsigned short* Ab = (const unsigned short*)Aptr;
        uint4 q[KS];
        #pragma unroll
        for (int i = 0; i < KS; ++i)
            q[i] = *(const uint4*)&Ab[(size_t)rowc * K + i * 32 + kq];
        __builtin_amdgcn_sched_barrier(0);   // all loads issued before converts
        #pragma unroll
        for (int i = 0; i < KS; ++i) {
            if (FUSE) {
                int kb = i * 32 + kq;
                float f0,f1,f2,f3,f4,f5,f6,f7;
                bf2_decode(q[i].x, f0, f1); bf2_decode(q[i].y, f2, f3);
                bf2_decode(q[i].z, f4, f5); bf2_decode(q[i].w, f6, f7);
                float4 sc0 = *(const float4*)&s_sc[kb];
                float4 sc1 = *(const float4*)&s_sc[kb + 4];
                float4 sh0 = *(const float4*)&s_sh[kb];
                float4 sh1 = *(const float4*)&s_sh[kb + 4];
                f0 = fmaxf(0.f, fmaf(f0, sc0.x, sh0.x));
                f1 = fmaxf(0.f, fmaf(f1, sc0.y, sh0.y));
                f2 = fmaxf(0.f, fmaf(f2, sc0.z, sh0.z));
                f3 = fmaxf(0.f, fmaf(f3, sc0.w, sh0.w));
                f4 = fmaxf(0.f, fmaf(f4, sc1.x, sh1.x));
                f5 = fmaxf(0.f, fmaf(f5, sc1.y, sh1.y));
                f6 = fmaxf(0.f, fmaf(f6, sc1.z, sh1.z));
                f7 = fmaxf(0.f, fmaf(f7, sc1.w, sh1.w));
                uint4 p;
                p.x = pack2bf(f0, f1); p.y = pack2bf(f2, f3);
                p.z = pack2bf(f4, f5); p.w = pack2bf(f6, f7);
                afr[i] = __builtin_bit_cast(short8, p);
            } else {
                afr[i] = __builtin_bit_cast(short8, q[i]);
            }
        }
    } else {
        const float* Af = (const float*)Aptr;
        float4 a0[KS], a1[KS];
        #pragma unroll
        for (int i = 0; i < KS; ++i) {
            a0[i] = *(const float4*)&Af[(size_t)rowc * K + i * 32 + kq];
            a1[i] = *(const float4*)&Af[(size_t)rowc * K + i * 32 + kq + 4];
        }
        __builtin_amdgcn_sched_barrier(0);   // all loads issued before converts
        #pragma unroll
        for (int i = 0; i < KS; ++i) {
            uint4 p;
            p.x = pack2bf(a0[i].x, a0[i].y); p.y = pack2bf(a0[i].z, a0[i].w);
            p.z = pack2bf(a1[i].x, a1[i].y); p.w = pack2bf(a1[i].z, a1[i].w);
            afr[i] = __builtin_bit_cast(short8, p);
        }
    }

    floatx4 acc[NT];
    #pragma unroll
    for (int nt = 0; nt < NT; ++nt) acc[nt] = (floatx4){0.f, 0.f, 0.f, 0.f};

    #pragma unroll
    for (int i = 0; i < KS; ++i) {
        #pragma unroll
        for (int nt = 0; nt < NT; ++nt) {
            short8 bfrag = *(const short8*)&Wt[(size_t)(nt * 16 + col) * K + i * 32 + kq];
            acc[nt] = __builtin_amdgcn_mfma_f32_16x16x32_bf16(afr[i], bfrag, acc[nt], 0, 0, 0);
        }
    }

    int obase = bid * 64 + wave * 16 + quad * 4;
    #pragma unroll
    for (int r = 0; r < 4; ++r) {
        int orow = obase + r;
        if (orow < M) {
            #pragma unroll
            for (int nt = 0; nt < NT; ++nt)
                Cb[(size_t)orow * NOUT + nt * 16 + col] = f2bf(acc[nt][r]);
        }
    }
}

template<int K, int NOUT, int FUSE, int ABF16>
__global__ __launch_bounds__(256, 3) void gemm_mfma_kernel(
        const void* __restrict__ Aptr, const unsigned short* __restrict__ Wt,
        unsigned short* __restrict__ Cb, int M,
        const float* __restrict__ sums, const float* __restrict__ sumsq,
        const float* __restrict__ gam, const float* __restrict__ bet, float invN) {
    gemm_body<K, NOUT, FUSE, ABF16>(blockIdx.x, Aptr, Wt, Cb, M, sums, sumsq, gam, bet, invN);
}

// ---- fused: blocks [0,GB) layer-1 GEMM, [GB,..) atomic-free CSR scatter ----
__global__ __launch_bounds__(256, 3) void gemm1_scatter_kernel(
        const float* __restrict__ x, const unsigned short* __restrict__ Wt1,
        unsigned short* __restrict__ Cb, int M, int GB,
        const int* __restrict__ src, const int* __restrict__ dst, int E,
        const int* __restrict__ rowstart, const int* __restrict__ rank,
        int* __restrict__ csr) {
    if ((int)blockIdx.x < GB) {
        gemm_body<D_IN, D_HID, 0, 0>(blockIdx.x, x, Wt1, Cb, M,
                                     nullptr, nullptr, nullptr, nullptr, 0.f);
    } else {
        int e = ((int)blockIdx.x - GB) * 256 + threadIdx.x;
        if (e < E) {
            int d = dst[e];
            csr[rowstart[d] + rank[e]] = src[e];   // no atomics
        }
    }
}

// ---------------- Aggregation (bf16 h, bf16 out, 4B CSR; w recomputed) -------------
// BNF=1: channel sums/sumsq reduced in padded LDS (stride 132 -> ~2-way bank
// aliasing, free) + one global atomic per channel per block (fuses bn_stats).
template<int D, int BNF>
__global__ __launch_bounds__(256) void agg_bf16_kernel(
        const unsigned short* __restrict__ h, const float* __restrict__ dinv,
        const int* __restrict__ rowstart, const int* __restrict__ csr,
        const float* __restrict__ bias,
        unsigned short* __restrict__ outb, int N,
        float* __restrict__ sums, float* __restrict__ sumsq) {
    constexpr int LPR = D / 8;           // lanes per row: 16 (D=128) / 8 (D=64)
    constexpr int RPB = 256 / LPR;       // rows per block: 16 / 32
    int lane = threadIdx.x & (LPR - 1);
    int r    = threadIdx.x / LPR;
    int v = blockIdx.x * RPB + r;
    int c0 = lane * 8;

    float acc[8] = {0.f,0.f,0.f,0.f,0.f,0.f,0.f,0.f};
    if (v < N) {
        const unsigned short* hc = h + c0;
        float dv = dinv[v];
        {   // self-loop term + bias
            float w = dv * dv;
            uint4 q = *(const uint4*)&hc[(size_t)v * D];
            float4 b0 = *(const float4*)&bias[c0];
            float4 b1 = *(const float4*)&bias[c0 + 4];
            acc[0]=b0.x; acc[1]=b0.y; acc[2]=b0.z; acc[3]=b0.w;
            acc[4]=b1.x; acc[5]=b1.y; acc[6]=b1.z; acc[7]=b1.w;
            accum8(acc, q, w);
        }
        int j  = rowstart[v];
        int j1 = rowstart[v + 1];
        for (; j + 4 <= j1; j += 4) {
            int s0 = csr[j],     s1 = csr[j + 1];
            int s2 = csr[j + 2], s3 = csr[j + 3];
            float w0 = dinv[s0] * dv, w1 = dinv[s1] * dv;
            float w2 = dinv[s2] * dv, w3 = dinv[s3] * dv;
            uint4 q0 = *(const uint4*)&hc[(size_t)s0 * D];
            uint4 q1 = *(const uint4*)&hc[(size_t)s1 * D];
            uint4 q2 = *(const uint4*)&hc[(size_t)s2 * D];
            uint4 q3 = *(const uint4*)&hc[(size_t)s3 * D];
            accum8(acc, q0, w0); accum8(acc, q1, w1);
            accum8(acc, q2, w2); accum8(acc, q3, w3);
        }
        for (; j < j1; ++j) {
            int s = csr[j];
            float w = dinv[s] * dv;
            uint4 q = *(const uint4*)&hc[(size_t)s * D];
            accum8(acc, q, w);
        }
        uint4 o;
        o.x = pack2bf(acc[0], acc[1]); o.y = pack2bf(acc[2], acc[3]);
        o.z = pack2bf(acc[4], acc[5]); o.w = pack2bf(acc[6], acc[7]);
        *(uint4*)&outb[(size_t)v * D + c0] = o;
    }

    if (BNF) {   // fused bn_stats (D==128, RPB==16)
        __shared__ float lsum[16 * 132];
        __shared__ float lsq [16 * 132];
        #pragma unroll
        for (int i = 0; i < 8; ++i) {
            lsum[r * 132 + c0 + i] = acc[i];
            lsq [r * 132 + c0 + i] = acc[i] * acc[i];
        }
        __syncthreads();
        int c = threadIdx.x;
        if (c < 128) {
            float s = 0.f, q = 0.f;
            #pragma unroll
            for (int rr = 0; rr < 16; ++rr) {
                s += lsum[rr * 132 + c];
                q += lsq [rr * 132 + c];
            }
            atomicAdd(&sums[c],  s);
            atomicAdd(&sumsq[c], q);
        }
    }
}

// ---------------- Global mean pool (bf16 input, D=64) ----------------
__global__ void pool_bf16_kernel(const unsigned short* __restrict__ x,
                                 const int* __restrict__ batch, int N,
                                 float* __restrict__ psum, int* __restrict__ pcnt) {
    __shared__ float ls[NGRAPH * 64];
    __shared__ int   lc[NGRAPH];
    for (int i = threadIdx.x; i < NGRAPH * 64; i += blockDim.x) ls[i] = 0.f;
    if (threadIdx.x < NGRAPH) lc[threadIdx.x] = 0;
    __syncthreads();
    int total = N * 32;
    for (int idx = blockIdx.x * blockDim.x + threadIdx.x; idx < total;
         idx += gridDim.x * blockDim.x) {
        int v = idx >> 5, cp = idx & 31;
        unsigned u = *(const unsigned*)&x[(size_t)v * 64 + cp * 2];
        float lo, hi; bf2_decode(u, lo, hi);
        int g = batch[v];
        atomicAdd(&ls[g * 64 + cp * 2],     lo);
        atomicAdd(&ls[g * 64 + cp * 2 + 1], hi);
        if (cp == 0) atomicAdd(&lc[g], 1);
    }
    __syncthreads();
    for (int i = threadIdx.x; i < NGRAPH * 64; i += blockDim.x) atomicAdd(&psum[i], ls[i]);
    if (threadIdx.x < NGRAPH) atomicAdd(&pcnt[threadIdx.x], lc[threadIdx.x]);
}

__global__ void pool_final_kernel(const float* __restrict__ psum, const int* __restrict__ pcnt,
                                  float* __restrict__ out) {
    int i = threadIdx.x;
    int g = i >> 6;
    float cnt = (float)max(pcnt[g], 1);
    out[i] = psum[i] / cnt;
}

// ---------------- launch ----------------
extern "C" void kernel_launch(void* const* d_in, const int* in_sizes, int n_in,
                              void* d_out, int out_size, void* d_ws, size_t ws_size,
                              hipStream_t stream) {
    const float* x   = (const float*)d_in[0];
    const int*   ei  = (const int*)d_in[1];
    const int*   bat = (const int*)d_in[2];
    const float* W1  = (const float*)d_in[3];
    const float* b1  = (const float*)d_in[4];
    const float* W2  = (const float*)d_in[5];
    const float* b2  = (const float*)d_in[6];
    const float* W3  = (const float*)d_in[7];
    const float* b3  = (const float*)d_in[8];
    const float* g1  = (const float*)d_in[9];
    const float* be1 = (const float*)d_in[10];
    const float* g2  = (const float*)d_in[11];
    const float* be2 = (const float*)d_in[12];
    float* out = (float*)d_out;

    int N = in_sizes[0] / D_IN;
    int E = in_sizes[1] / 2;
    const int* src = ei;
    const int* dst = ei + E;

    char* p = (char*)d_ws;
    auto alloc = [&](size_t bytes) { char* r = p; p += (bytes + 255) & ~(size_t)255; return r; };
    int NB = (N + SCAN_TPB * SCAN_VPT - 1) / (SCAN_TPB * SCAN_VPT);
    int*   deg      = (int*)  alloc((size_t)N * 4);
    int*   rowstart = (int*)  alloc((size_t)(N + 1) * 4);
    int*   rank     = (int*)  alloc((size_t)E * 4);
    float* dinv     = (float*)alloc((size_t)N * 4);
    int*   bsum     = (int*)  alloc((size_t)NB * 4);
    int*   bprefix  = (int*)  alloc((size_t)NB * 4);
    int*   csr      = (int*)  alloc((size_t)E * 4);
    unsigned short* hb16   = (unsigned short*)alloc((size_t)N * 128 * 2);  // GEMM out
    unsigned short* aggb16 = (unsigned short*)alloc((size_t)N * 128 * 2);  // agg out
    unsigned short* Wt1 = (unsigned short*)alloc((size_t)D_HID * D_IN * 2);
    unsigned short* Wt2 = (unsigned short*)alloc((size_t)D_HID * D_HID * 2);
    unsigned short* Wt3 = (unsigned short*)alloc((size_t)D_OUT_ * D_HID * 2);
    float* sums     = (float*)alloc(128 * 4);
    float* sumsq    = (float*)alloc(128 * 4);
    float* psum     = (float*)alloc(NGRAPH * 64 * 4);
    int*   pcnt     = (int*)  alloc(NGRAPH * 4);

    int tpb = 256;
    int ebl = (E + tpb - 1) / tpb;
    int nbl = (N + tpb - 1) / tpb;
    int gblocks = (N + 63) / 64;
    float invN = 1.0f / (float)N;

    // ---- weight prep ----
    wprep_kernel<<<(D_IN * D_HID + 255) / 256, 256, 0, stream>>>(W1, D_IN, D_HID, Wt1);
    wprep_kernel<<<(D_HID * D_HID + 255) / 256, 256, 0, stream>>>(W2, D_HID, D_HID, Wt2);
    wprep_kernel<<<(D_HID * D_OUT_ + 255) / 256, 256, 0, stream>>>(W3, D_HID, D_OUT_, Wt3);

    // ---- CSR build ----
    (void)hipMemsetAsync(deg, 0, (size_t)N * 4, stream);
    (void)hipMemsetAsync(sums, 0, 128 * 4, stream);
    (void)hipMemsetAsync(sumsq, 0, 128 * 4, stream);
    count_rank_kernel<<<ebl, tpb, 0, stream>>>(dst, E, deg, rank);
    dinv_kernel<<<nbl, tpb, 0, stream>>>(deg, N, dinv);
    block_sum_kernel<<<NB, SCAN_TPB, 0, stream>>>(deg, N, bsum);
    scan_bsum_kernel<<<1, SCAN_TPB, 0, stream>>>(bsum, NB, bprefix, rowstart, N, E);
    local_scan_kernel<<<NB, SCAN_TPB, 0, stream>>>(deg, N, bprefix, rowstart);

    // ---- Layer-1 GEMM fused with atomic-free CSR scatter ----
    gemm1_scatter_kernel<<<gblocks + ebl, 256, 0, stream>>>(
        x, Wt1, hb16, N, gblocks, src, dst, E, rowstart, rank, csr);

    // ---- Layer 1 agg (+fused bn_stats) ----
    agg_bf16_kernel<D_HID, 1><<<(N + 15) / 16, 256, 0, stream>>>(
        hb16, dinv, rowstart, csr, b1, aggb16, N, sums, sumsq);

    // ---- Layer 2 (BN-final + ReLU fused into GEMM) ----
    gemm_mfma_kernel<D_HID, D_HID, 1, 1><<<gblocks, 256, 0, stream>>>(
        aggb16, Wt2, hb16, N, sums, sumsq, g1, be1, invN);
    (void)hipMemsetAsync(sums, 0, 128 * 4, stream);
    (void)hipMemsetAsync(sumsq, 0, 128 * 4, stream);
    agg_bf16_kernel<D_HID, 1><<<(N + 15) / 16, 256, 0, stream>>>(
        hb16, dinv, rowstart, csr, b2, aggb16, N, sums, sumsq);

    // ---- Layer 3 ----
    gemm_mfma_kernel<D_HID, D_OUT_, 1, 1><<<gblocks, 256, 0, stream>>>(
        aggb16, Wt3, hb16, N, sums, sumsq, g2, be2, invN);
    agg_bf16_kernel<D_OUT_, 0><<<(N + 31) / 32, 256, 0, stream>>>(
        hb16, dinv, rowstart, csr, b3, aggb16, N, nullptr, nullptr);

    // ---- Pool ----
    (void)hipMemsetAsync(psum, 0, NGRAPH * 64 * 4, stream);
    (void)hipMemsetAsync(pcnt, 0, NGRAPH * 4, stream);
    pool_bf16_kernel<<<256, 256, 0, stream>>>(aggb16, bat, N, psum, pcnt);
    pool_final_kernel<<<1, NGRAPH * 64, 0, stream>>>(psum, pcnt, out);
}

// Round 10
// 394.246 us; speedup vs baseline: 1.1866x; 1.1866x over previous
//
#include <hip/hip_runtime.h>
#include <hip/hip_bf16.h>

#define D_IN   256
#define D_HID  128
#define D_OUT_ 64
#define NGRAPH 16
#define BN_EPS 1e-5f

#define SCAN_TPB 256
#define SCAN_VPT 4            // 1024 elements per block

typedef __attribute__((ext_vector_type(8))) short short8;
typedef __attribute__((ext_vector_type(4))) float floatx4;

// ---------------- helpers ----------------
__device__ __forceinline__ unsigned short f2bf(float x) {   // RNE f32->bf16
    unsigned u = __float_as_uint(x);
    return (unsigned short)((u + 0x7fffu + ((u >> 16) & 1u)) >> 16);
}
__device__ __forceinline__ unsigned pack2bf(float lo, float hi) {
    return (unsigned)f2bf(lo) | ((unsigned)f2bf(hi) << 16);
}
__device__ __forceinline__ void bf2_decode(unsigned u, float& lo, float& hi) {
    lo = __uint_as_float(u << 16);
    hi = __uint_as_float(u & 0xffff0000u);
}
// acc[0..7] += wt * bf16x8(qv)
__device__ __forceinline__ void accum8(float* acc, uint4 qv, float wt) {
    float f0,f1,f2,f3,f4,f5,f6,f7;
    bf2_decode(qv.x, f0, f1); bf2_decode(qv.y, f2, f3);
    bf2_decode(qv.z, f4, f5); bf2_decode(qv.w, f6, f7);
    acc[0]=fmaf(f0,wt,acc[0]); acc[1]=fmaf(f1,wt,acc[1]);
    acc[2]=fmaf(f2,wt,acc[2]); acc[3]=fmaf(f3,wt,acc[3]);
    acc[4]=fmaf(f4,wt,acc[4]); acc[5]=fmaf(f5,wt,acc[5]);
    acc[6]=fmaf(f6,wt,acc[6]); acc[7]=fmaf(f7,wt,acc[7]);
}

// ---------------- CSR build ----------------
// rank[e] = arrival order of edge e within its dst row (atomicAdd return value)
// -> later scatter is atomic-free (r9-verified win).
__global__ void count_rank_kernel(const int* __restrict__ dst, int E,
                                  int* __restrict__ deg, int* __restrict__ rank) {
    int e = blockIdx.x * blockDim.x + threadIdx.x;
    if (e < E) rank[e] = atomicAdd(&deg[dst[e]], 1);
}

__global__ void dinv_kernel(const int* __restrict__ deg, int N, float* __restrict__ dinv) {
    int v = blockIdx.x * blockDim.x + threadIdx.x;
    if (v < N) dinv[v] = rsqrtf((float)(deg[v] + 1));   // +1 self-loop
}

__global__ void block_sum_kernel(const int* __restrict__ deg, int N, int* __restrict__ bsum) {
    __shared__ int red[SCAN_TPB];
    int t = threadIdx.x;
    int base = blockIdx.x * (SCAN_TPB * SCAN_VPT) + t;
    int s = 0;
    #pragma unroll
    for (int i = 0; i < SCAN_VPT; ++i) {
        int idx = base + i * SCAN_TPB;
        if (idx < N) s += deg[idx];
    }
    red[t] = s;
    __syncthreads();
    for (int off = SCAN_TPB / 2; off > 0; off >>= 1) {
        if (t < off) red[t] += red[t + off];
        __syncthreads();
    }
    if (t == 0) bsum[blockIdx.x] = red[0];
}

__global__ void scan_bsum_kernel(const int* __restrict__ bsum, int NB,
                                 int* __restrict__ bprefix,
                                 int* __restrict__ rowstart, int N, int E) {
    __shared__ int part[SCAN_TPB];
    int t = threadIdx.x;
    int s = (t < NB) ? bsum[t] : 0;
    part[t] = s;
    __syncthreads();
    for (int off = 1; off < SCAN_TPB; off <<= 1) {
        int x = (t >= off) ? part[t - off] : 0;
        __syncthreads();
        part[t] += x;
        __syncthreads();
    }
    if (t < NB) bprefix[t] = part[t] - s;   // exclusive prefix of block sums
    if (t == 0) rowstart[N] = E;            // total degree == E analytically
}

__global__ void local_scan_kernel(const int* __restrict__ deg, int N,
                                  const int* __restrict__ bprefix,
                                  int* __restrict__ rowstart) {
    __shared__ int part[SCAN_TPB];
    int t = threadIdx.x;
    int base = blockIdx.x * (SCAN_TPB * SCAN_VPT) + t * SCAN_VPT;
    int v[SCAN_VPT];
    int s = 0;
    #pragma unroll
    for (int i = 0; i < SCAN_VPT; ++i) {
        v[i] = (base + i < N) ? deg[base + i] : 0;
        s += v[i];
    }
    part[t] = s;
    __syncthreads();
    for (int off = 1; off < SCAN_TPB; off <<= 1) {   // inclusive Hillis-Steele
        int x = (t >= off) ? part[t - off] : 0;
        __syncthreads();
        part[t] += x;
        __syncthreads();
    }
    int excl = part[t] - s + bprefix[blockIdx.x];
    #pragma unroll
    for (int i = 0; i < SCAN_VPT; ++i) {
        if (base + i < N) rowstart[base + i] = excl;
        excl += v[i];
    }
}

// ---------------- weight prep: W[K][NOUT] f32 -> Wt[NOUT][K] bf16 ----------------
__global__ void wprep_kernel(const float* __restrict__ W, int K, int NOUT,
                             unsigned short* __restrict__ Wt) {
    int idx = blockIdx.x * blockDim.x + threadIdx.x;
    if (idx >= K * NOUT) return;
    int k = idx / NOUT, n = idx - k * NOUT;
    Wt[(size_t)n * K + k] = f2bf(W[idx]);
}

// ---------------- MFMA GEMM body: Cb[M][NOUT] bf16 = act(A)[M][K] @ Wt^T ----------
// FUSE: BN scale/shift computed per block from raw sums/sumsq into LDS.
// Layouts: A[m=lane&15][k=quad*8+j], B[k=quad*8+j][n=lane&15], C/D col=lane&15 row=quad*4+reg.
template<int K, int NOUT, int FUSE, int ABF16>
__device__ __forceinline__ void gemm_body(
        int bid, const void* __restrict__ Aptr, const unsigned short* __restrict__ Wt,
        unsigned short* __restrict__ Cb, int M,
        const float* __restrict__ sums, const float* __restrict__ sumsq,
        const float* __restrict__ gam, const float* __restrict__ bet, float invN) {
    constexpr int NT = NOUT / 16;
    constexpr int KS = K / 32;
    __shared__ float s_sc[FUSE ? K : 1];
    __shared__ float s_sh[FUSE ? K : 1];
    if (FUSE) {
        int t = threadIdx.x;
        if (t < K) {
            float mu  = sums[t] * invN;
            float var = sumsq[t] * invN - mu * mu;
            float sc  = gam[t] * rsqrtf(var + BN_EPS);
            s_sc[t] = sc;
            s_sh[t] = fmaf(-mu, sc, bet[t]);
        }
        __syncthreads();
    }
    int lane = threadIdx.x & 63;
    int wave = threadIdx.x >> 6;
    int col  = lane & 15;
    int quad = lane >> 4;
    int kq   = quad * 8;
    int row  = bid * 64 + wave * 16 + col;
    int rowc = min(row, M - 1);

    short8 afr[KS];
    if (ABF16) {
        const unsigned short* Ab = (const unsigned short*)Aptr;
        uint4 q[KS];
        #pragma unroll
        for (int i = 0; i < KS; ++i)
            q[i] = *(const uint4*)&Ab[(size_t)rowc * K + i * 32 + kq];
        __builtin_amdgcn_sched_barrier(0);   // all loads issued before converts
        #pragma unroll
        for (int i = 0; i < KS; ++i) {
            if (FUSE) {
                int kb = i * 32 + kq;
                float f0,f1,f2,f3,f4,f5,f6,f7;
                bf2_decode(q[i].x, f0, f1); bf2_decode(q[i].y, f2, f3);
                bf2_decode(q[i].z, f4, f5); bf2_decode(q[i].w, f6, f7);
                float4 sc0 = *(const float4*)&s_sc[kb];
                float4 sc1 = *(const float4*)&s_sc[kb + 4];
                float4 sh0 = *(const float4*)&s_sh[kb];
                float4 sh1 = *(const float4*)&s_sh[kb + 4];
                f0 = fmaxf(0.f, fmaf(f0, sc0.x, sh0.x));
                f1 = fmaxf(0.f, fmaf(f1, sc0.y, sh0.y));
                f2 = fmaxf(0.f, fmaf(f2, sc0.z, sh0.z));
                f3 = fmaxf(0.f, fmaf(f3, sc0.w, sh0.w));
                f4 = fmaxf(0.f, fmaf(f4, sc1.x, sh1.x));
                f5 = fmaxf(0.f, fmaf(f5, sc1.y, sh1.y));
                f6 = fmaxf(0.f, fmaf(f6, sc1.z, sh1.z));
                f7 = fmaxf(0.f, fmaf(f7, sc1.w, sh1.w));
                uint4 p;
                p.x = pack2bf(f0, f1); p.y = pack2bf(f2, f3);
                p.z = pack2bf(f4, f5); p.w = pack2bf(f6, f7);
                afr[i] = __builtin_bit_cast(short8, p);
            } else {
                afr[i] = __builtin_bit_cast(short8, q[i]);
            }
        }
    } else {
        const float* Af = (const float*)Aptr;
        float4 a0[KS], a1[KS];
        #pragma unroll
        for (int i = 0; i < KS; ++i) {
            a0[i] = *(const float4*)&Af[(size_t)rowc * K + i * 32 + kq];
            a1[i] = *(const float4*)&Af[(size_t)rowc * K + i * 32 + kq + 4];
        }
        __builtin_amdgcn_sched_barrier(0);   // all loads issued before converts
        #pragma unroll
        for (int i = 0; i < KS; ++i) {
            uint4 p;
            p.x = pack2bf(a0[i].x, a0[i].y); p.y = pack2bf(a0[i].z, a0[i].w);
            p.z = pack2bf(a1[i].x, a1[i].y); p.w = pack2bf(a1[i].z, a1[i].w);
            afr[i] = __builtin_bit_cast(short8, p);
        }
    }

    floatx4 acc[NT];
    #pragma unroll
    for (int nt = 0; nt < NT; ++nt) acc[nt] = (floatx4){0.f, 0.f, 0.f, 0.f};

    #pragma unroll
    for (int i = 0; i < KS; ++i) {
        #pragma unroll
        for (int nt = 0; nt < NT; ++nt) {
            short8 bfrag = *(const short8*)&Wt[(size_t)(nt * 16 + col) * K + i * 32 + kq];
            acc[nt] = __builtin_amdgcn_mfma_f32_16x16x32_bf16(afr[i], bfrag, acc[nt], 0, 0, 0);
        }
    }

    int obase = bid * 64 + wave * 16 + quad * 4;
    #pragma unroll
    for (int r = 0; r < 4; ++r) {
        int orow = obase + r;
        if (orow < M) {
            #pragma unroll
            for (int nt = 0; nt < NT; ++nt)
                Cb[(size_t)orow * NOUT + nt * 16 + col] = f2bf(acc[nt][r]);
        }
    }
}

template<int K, int NOUT, int FUSE, int ABF16>
__global__ __launch_bounds__(256, 3) void gemm_mfma_kernel(
        const void* __restrict__ Aptr, const unsigned short* __restrict__ Wt,
        unsigned short* __restrict__ Cb, int M,
        const float* __restrict__ sums, const float* __restrict__ sumsq,
        const float* __restrict__ gam, const float* __restrict__ bet, float invN) {
    gemm_body<K, NOUT, FUSE, ABF16>(blockIdx.x, Aptr, Wt, Cb, M, sums, sumsq, gam, bet, invN);
}

// ---- fused: blocks [0,GB) layer-1 GEMM, [GB,..) atomic-free CSR scatter ----
__global__ __launch_bounds__(256, 3) void gemm1_scatter_kernel(
        const float* __restrict__ x, const unsigned short* __restrict__ Wt1,
        unsigned short* __restrict__ Cb, int M, int GB,
        const int* __restrict__ src, const int* __restrict__ dst, int E,
        const int* __restrict__ rowstart, const int* __restrict__ rank,
        int* __restrict__ csr) {
    if ((int)blockIdx.x < GB) {
        gemm_body<D_IN, D_HID, 0, 0>(blockIdx.x, x, Wt1, Cb, M,
                                     nullptr, nullptr, nullptr, nullptr, 0.f);
    } else {
        int e = ((int)blockIdx.x - GB) * 256 + threadIdx.x;
        if (e < E) {
            int d = dst[e];
            csr[rowstart[d] + rank[e]] = src[e];   // no atomics
        }
    }
}

// ---------------- Aggregation (bf16 h, bf16 out, 4B CSR; w recomputed) -------------
// NO barrier / NO fused bn_stats: r9 showed a block-wide __syncthreads turns
// degree skew into stall time (92 vs ~60 us). Waves finish independently.
template<int D>
__global__ __launch_bounds__(256) void agg_bf16_kernel(
        const unsigned short* __restrict__ h, const float* __restrict__ dinv,
        const int* __restrict__ rowstart, const int* __restrict__ csr,
        const float* __restrict__ bias,
        unsigned short* __restrict__ outb, int N) {
    constexpr int LPR = D / 8;           // lanes per row: 16 (D=128) / 8 (D=64)
    constexpr int RPB = 256 / LPR;       // rows per block: 16 / 32
    int lane = threadIdx.x & (LPR - 1);
    int r    = threadIdx.x / LPR;
    int v = blockIdx.x * RPB + r;
    if (v >= N) return;
    int c0 = lane * 8;
    const unsigned short* hc = h + c0;
    float dv = dinv[v];

    float acc[8];
    {   // self-loop term + bias
        float w = dv * dv;
        uint4 q = *(const uint4*)&hc[(size_t)v * D];
        float4 b0 = *(const float4*)&bias[c0];
        float4 b1 = *(const float4*)&bias[c0 + 4];
        acc[0]=b0.x; acc[1]=b0.y; acc[2]=b0.z; acc[3]=b0.w;
        acc[4]=b1.x; acc[5]=b1.y; acc[6]=b1.z; acc[7]=b1.w;
        accum8(acc, q, w);
    }

    int j  = rowstart[v];
    int j1 = rowstart[v + 1];
    for (; j + 4 <= j1; j += 4) {
        int s0 = csr[j],     s1 = csr[j + 1];
        int s2 = csr[j + 2], s3 = csr[j + 3];
        float w0 = dinv[s0] * dv, w1 = dinv[s1] * dv;
        float w2 = dinv[s2] * dv, w3 = dinv[s3] * dv;
        uint4 q0 = *(const uint4*)&hc[(size_t)s0 * D];
        uint4 q1 = *(const uint4*)&hc[(size_t)s1 * D];
        uint4 q2 = *(const uint4*)&hc[(size_t)s2 * D];
        uint4 q3 = *(const uint4*)&hc[(size_t)s3 * D];
        accum8(acc, q0, w0); accum8(acc, q1, w1);
        accum8(acc, q2, w2); accum8(acc, q3, w3);
    }
    for (; j < j1; ++j) {
        int s = csr[j];
        float w = dinv[s] * dv;
        uint4 q = *(const uint4*)&hc[(size_t)s * D];
        accum8(acc, q, w);
    }

    uint4 o;
    o.x = pack2bf(acc[0], acc[1]); o.y = pack2bf(acc[2], acc[3]);
    o.z = pack2bf(acc[4], acc[5]); o.w = pack2bf(acc[6], acc[7]);
    *(uint4*)&outb[(size_t)v * D + c0] = o;
}

// ---------------- BatchNorm stats (bf16 input, D=128) ----------------
__global__ void bn_stats_bf16_kernel(const unsigned short* __restrict__ x, int N,
                                     float* __restrict__ sums, float* __restrict__ sumsq) {
    __shared__ float ls0[256], ls1[256], lq0[256], lq1[256];
    int pr = threadIdx.x & 63;           // channel pair
    int rg = threadIdx.x >> 6;           // row group 0..3
    float s0=0.f, s1=0.f, q0=0.f, q1=0.f;
    for (int v = blockIdx.x * 4 + rg; v < N; v += gridDim.x * 4) {
        unsigned u = *(const unsigned*)&x[(size_t)v * 128 + pr * 2];
        float lo, hi; bf2_decode(u, lo, hi);
        s0 += lo; s1 += hi;
        q0 = fmaf(lo, lo, q0); q1 = fmaf(hi, hi, q1);
    }
    ls0[threadIdx.x]=s0; ls1[threadIdx.x]=s1; lq0[threadIdx.x]=q0; lq1[threadIdx.x]=q1;
    __syncthreads();
    if (threadIdx.x < 64) {
        int pp = threadIdx.x;
        float a0=0,a1=0,b0=0,b1=0;
        #pragma unroll
        for (int g = 0; g < 4; ++g) {
            a0 += ls0[g*64+pp]; a1 += ls1[g*64+pp];
            b0 += lq0[g*64+pp]; b1 += lq1[g*64+pp];
        }
        atomicAdd(&sums[pp*2],  a0); atomicAdd(&sums[pp*2+1],  a1);
        atomicAdd(&sumsq[pp*2], b0); atomicAdd(&sumsq[pp*2+1], b1);
    }
}

// ---------------- Global mean pool (bf16 input, D=64) ----------------
__global__ void pool_bf16_kernel(const unsigned short* __restrict__ x,
                                 const int* __restrict__ batch, int N,
                                 float* __restrict__ psum, int* __restrict__ pcnt) {
    __shared__ float ls[NGRAPH * 64];
    __shared__ int   lc[NGRAPH];
    for (int i = threadIdx.x; i < NGRAPH * 64; i += blockDim.x) ls[i] = 0.f;
    if (threadIdx.x < NGRAPH) lc[threadIdx.x] = 0;
    __syncthreads();
    int total = N * 32;
    for (int idx = blockIdx.x * blockDim.x + threadIdx.x; idx < total;
         idx += gridDim.x * blockDim.x) {
        int v = idx >> 5, cp = idx & 31;
        unsigned u = *(const unsigned*)&x[(size_t)v * 64 + cp * 2];
        float lo, hi; bf2_decode(u, lo, hi);
        int g = batch[v];
        atomicAdd(&ls[g * 64 + cp * 2],     lo);
        atomicAdd(&ls[g * 64 + cp * 2 + 1], hi);
        if (cp == 0) atomicAdd(&lc[g], 1);
    }
    __syncthreads();
    for (int i = threadIdx.x; i < NGRAPH * 64; i += blockDim.x) atomicAdd(&psum[i], ls[i]);
    if (threadIdx.x < NGRAPH) atomicAdd(&pcnt[threadIdx.x], lc[threadIdx.x]);
}

__global__ void pool_final_kernel(const float* __restrict__ psum, const int* __restrict__ pcnt,
                                  float* __restrict__ out) {
    int i = threadIdx.x;
    int g = i >> 6;
    float cnt = (float)max(pcnt[g], 1);
    out[i] = psum[i] / cnt;
}

// ---------------- launch ----------------
extern "C" void kernel_launch(void* const* d_in, const int* in_sizes, int n_in,
                              void* d_out, int out_size, void* d_ws, size_t ws_size,
                              hipStream_t stream) {
    const float* x   = (const float*)d_in[0];
    const int*   ei  = (const int*)d_in[1];
    const int*   bat = (const int*)d_in[2];
    const float* W1  = (const float*)d_in[3];
    const float* b1  = (const float*)d_in[4];
    const float* W2  = (const float*)d_in[5];
    const float* b2  = (const float*)d_in[6];
    const float* W3  = (const float*)d_in[7];
    const float* b3  = (const float*)d_in[8];
    const float* g1  = (const float*)d_in[9];
    const float* be1 = (const float*)d_in[10];
    const float* g2  = (const float*)d_in[11];
    const float* be2 = (const float*)d_in[12];
    float* out = (float*)d_out;

    int N = in_sizes[0] / D_IN;
    int E = in_sizes[1] / 2;
    const int* src = ei;
    const int* dst = ei + E;

    char* p = (char*)d_ws;
    auto alloc = [&](size_t bytes) { char* r = p; p += (bytes + 255) & ~(size_t)255; return r; };
    int NB = (N + SCAN_TPB * SCAN_VPT - 1) / (SCAN_TPB * SCAN_VPT);
    int*   deg      = (int*)  alloc((size_t)N * 4);
    int*   rowstart = (int*)  alloc((size_t)(N + 1) * 4);
    int*   rank     = (int*)  alloc((size_t)E * 4);
    float* dinv     = (float*)alloc((size_t)N * 4);
    int*   bsum     = (int*)  alloc((size_t)NB * 4);
    int*   bprefix  = (int*)  alloc((size_t)NB * 4);
    int*   csr      = (int*)  alloc((size_t)E * 4);
    unsigned short* hb16   = (unsigned short*)alloc((size_t)N * 128 * 2);  // GEMM out
    unsigned short* aggb16 = (unsigned short*)alloc((size_t)N * 128 * 2);  // agg out
    unsigned short* Wt1 = (unsigned short*)alloc((size_t)D_HID * D_IN * 2);
    unsigned short* Wt2 = (unsigned short*)alloc((size_t)D_HID * D_HID * 2);
    unsigned short* Wt3 = (unsigned short*)alloc((size_t)D_OUT_ * D_HID * 2);
    float* sums     = (float*)alloc(128 * 4);
    float* sumsq    = (float*)alloc(128 * 4);
    float* psum     = (float*)alloc(NGRAPH * 64 * 4);
    int*   pcnt     = (int*)  alloc(NGRAPH * 4);

    int tpb = 256;
    int ebl = (E + tpb - 1) / tpb;
    int nbl = (N + tpb - 1) / tpb;
    int gblocks = (N + 63) / 64;
    float invN = 1.0f / (float)N;

    // ---- weight prep ----
    wprep_kernel<<<(D_IN * D_HID + 255) / 256, 256, 0, stream>>>(W1, D_IN, D_HID, Wt1);
    wprep_kernel<<<(D_HID * D_HID + 255) / 256, 256, 0, stream>>>(W2, D_HID, D_HID, Wt2);
    wprep_kernel<<<(D_HID * D_OUT_ + 255) / 256, 256, 0, stream>>>(W3, D_HID, D_OUT_, Wt3);

    // ---- CSR build ----
    (void)hipMemsetAsync(deg, 0, (size_t)N * 4, stream);
    count_rank_kernel<<<ebl, tpb, 0, stream>>>(dst, E, deg, rank);
    dinv_kernel<<<nbl, tpb, 0, stream>>>(deg, N, dinv);
    block_sum_kernel<<<NB, SCAN_TPB, 0, stream>>>(deg, N, bsum);
    scan_bsum_kernel<<<1, SCAN_TPB, 0, stream>>>(bsum, NB, bprefix, rowstart, N, E);
    local_scan_kernel<<<NB, SCAN_TPB, 0, stream>>>(deg, N, bprefix, rowstart);

    // ---- Layer-1 GEMM fused with atomic-free CSR scatter ----
    gemm1_scatter_kernel<<<gblocks + ebl, 256, 0, stream>>>(
        x, Wt1, hb16, N, gblocks, src, dst, E, rowstart, rank, csr);

    // ---- Layer 1 ----
    agg_bf16_kernel<D_HID><<<(N + 15) / 16, 256, 0, stream>>>(
        hb16, dinv, rowstart, csr, b1, aggb16, N);
    (void)hipMemsetAsync(sums, 0, 128 * 4, stream);
    (void)hipMemsetAsync(sumsq, 0, 128 * 4, stream);
    bn_stats_bf16_kernel<<<256, 256, 0, stream>>>(aggb16, N, sums, sumsq);

    // ---- Layer 2 (BN-final + ReLU fused into GEMM) ----
    gemm_mfma_kernel<D_HID, D_HID, 1, 1><<<gblocks, 256, 0, stream>>>(
        aggb16, Wt2, hb16, N, sums, sumsq, g1, be1, invN);
    agg_bf16_kernel<D_HID><<<(N + 15) / 16, 256, 0, stream>>>(
        hb16, dinv, rowstart, csr, b2, aggb16, N);
    (void)hipMemsetAsync(sums, 0, 128 * 4, stream);
    (void)hipMemsetAsync(sumsq, 0, 128 * 4, stream);
    bn_stats_bf16_kernel<<<256, 256, 0, stream>>>(aggb16, N, sums, sumsq);

    // ---- Layer 3 ----
    gemm_mfma_kernel<D_HID, D_OUT_, 1, 1><<<gblocks, 256, 0, stream>>>(
        aggb16, Wt3, hb16, N, sums, sumsq, g2, be2, invN);
    agg_bf16_kernel<D_OUT_><<<(N + 31) / 32, 256, 0, stream>>>(
        hb16, dinv, rowstart, csr, b3, aggb16, N);

    // ---- Pool ----
    (void)hipMemsetAsync(psum, 0, NGRAPH * 64 * 4, stream);
    (void)hipMemsetAsync(pcnt, 0, NGRAPH * 4, stream);
    pool_bf16_kernel<<<256, 256, 0, stream>>>(aggb16, bat, N, psum, pcnt);
    pool_final_kernel<<<1, NGRAPH * 64, 0, stream>>>(psum, pcnt, out);
}

// Round 11
// 385.820 us; speedup vs baseline: 1.2125x; 1.0218x over previous
//
#include <hip/hip_runtime.h>
#include <hip/hip_bf16.h>

#define D_IN   256
#define D_HID  128
#define D_OUT_ 64
#define NGRAPH 16
#define BN_EPS 1e-5f

#define SCAN_TPB 256
#define SCAN_VPT 4            // 1024 elements per block

typedef __attribute__((ext_vector_type(8))) short short8;
typedef __attribute__((ext_vector_type(4))) float floatx4;

// ---------------- helpers ----------------
__device__ __forceinline__ unsigned short f2bf(float x) {   // RNE f32->bf16
    unsigned u = __float_as_uint(x);
    return (unsigned short)((u + 0x7fffu + ((u >> 16) & 1u)) >> 16);
}
__device__ __forceinline__ unsigned pack2bf(float lo, float hi) {
    return (unsigned)f2bf(lo) | ((unsigned)f2bf(hi) << 16);
}
__device__ __forceinline__ void bf2_decode(unsigned u, float& lo, float& hi) {
    lo = __uint_as_float(u << 16);
    hi = __uint_as_float(u & 0xffff0000u);
}
// acc[0..7] += wt * bf16x8(qv)
__device__ __forceinline__ void accum8(float* acc, uint4 qv, float wt) {
    float f0,f1,f2,f3,f4,f5,f6,f7;
    bf2_decode(qv.x, f0, f1); bf2_decode(qv.y, f2, f3);
    bf2_decode(qv.z, f4, f5); bf2_decode(qv.w, f6, f7);
    acc[0]=fmaf(f0,wt,acc[0]); acc[1]=fmaf(f1,wt,acc[1]);
    acc[2]=fmaf(f2,wt,acc[2]); acc[3]=fmaf(f3,wt,acc[3]);
    acc[4]=fmaf(f4,wt,acc[4]); acc[5]=fmaf(f5,wt,acc[5]);
    acc[6]=fmaf(f6,wt,acc[6]); acc[7]=fmaf(f7,wt,acc[7]);
}

// ---------------- CSR build ----------------
// rank[e] = arrival order of edge e within its dst row -> atomic-free scatter.
__global__ void count_rank_kernel(const int* __restrict__ dst, int E,
                                  int* __restrict__ deg, int* __restrict__ rank) {
    int e = blockIdx.x * blockDim.x + threadIdx.x;
    if (e < E) rank[e] = atomicAdd(&deg[dst[e]], 1);
}

// fused: dinv for 1024 nodes + block sum for the scan (both depend only on deg)
__global__ void dinv_bsum_kernel(const int* __restrict__ deg, int N,
                                 float* __restrict__ dinv, int* __restrict__ bsum) {
    __shared__ int red[SCAN_TPB];
    int t = threadIdx.x;
    int base = blockIdx.x * (SCAN_TPB * SCAN_VPT) + t;
    int s = 0;
    #pragma unroll
    for (int i = 0; i < SCAN_VPT; ++i) {
        int idx = base + i * SCAN_TPB;
        if (idx < N) {
            int d = deg[idx];
            dinv[idx] = rsqrtf((float)(d + 1));   // +1 self-loop
            s += d;
        }
    }
    red[t] = s;
    __syncthreads();
    for (int off = SCAN_TPB / 2; off > 0; off >>= 1) {
        if (t < off) red[t] += red[t + off];
        __syncthreads();
    }
    if (t == 0) bsum[blockIdx.x] = red[0];
}

__global__ void scan_bsum_kernel(const int* __restrict__ bsum, int NB,
                                 int* __restrict__ bprefix,
                                 int* __restrict__ rowstart, int N, int E) {
    __shared__ int part[SCAN_TPB];
    int t = threadIdx.x;
    int s = (t < NB) ? bsum[t] : 0;
    part[t] = s;
    __syncthreads();
    for (int off = 1; off < SCAN_TPB; off <<= 1) {
        int x = (t >= off) ? part[t - off] : 0;
        __syncthreads();
        part[t] += x;
        __syncthreads();
    }
    if (t < NB) bprefix[t] = part[t] - s;   // exclusive prefix of block sums
    if (t == 0) rowstart[N] = E;            // total degree == E analytically
}

__global__ void local_scan_kernel(const int* __restrict__ deg, int N,
                                  const int* __restrict__ bprefix,
                                  int* __restrict__ rowstart) {
    __shared__ int part[SCAN_TPB];
    int t = threadIdx.x;
    int base = blockIdx.x * (SCAN_TPB * SCAN_VPT) + t * SCAN_VPT;
    int v[SCAN_VPT];
    int s = 0;
    #pragma unroll
    for (int i = 0; i < SCAN_VPT; ++i) {
        v[i] = (base + i < N) ? deg[base + i] : 0;
        s += v[i];
    }
    part[t] = s;
    __syncthreads();
    for (int off = 1; off < SCAN_TPB; off <<= 1) {   // inclusive Hillis-Steele
        int x = (t >= off) ? part[t - off] : 0;
        __syncthreads();
        part[t] += x;
        __syncthreads();
    }
    int excl = part[t] - s + bprefix[blockIdx.x];
    #pragma unroll
    for (int i = 0; i < SCAN_VPT; ++i) {
        if (base + i < N) rowstart[base + i] = excl;
        excl += v[i];
    }
}

// ---------------- weight prep: all three weights in ONE dispatch ----------------
// W[K][NOUT] f32 -> Wt[NOUT][K] bf16
__global__ void wprep_all_kernel(const float* __restrict__ W1, const float* __restrict__ W2,
                                 const float* __restrict__ W3,
                                 unsigned short* __restrict__ Wt1,
                                 unsigned short* __restrict__ Wt2,
                                 unsigned short* __restrict__ Wt3) {
    int idx = blockIdx.x * blockDim.x + threadIdx.x;
    const int S1 = D_IN * D_HID;          // 32768
    const int S2 = D_HID * D_HID;         // 16384
    const int S3 = D_HID * D_OUT_;        // 8192
    if (idx < S1) {
        int k = idx / D_HID, n = idx - k * D_HID;
        Wt1[(size_t)n * D_IN + k] = f2bf(W1[idx]);
    } else if (idx < S1 + S2) {
        int i = idx - S1;
        int k = i / D_HID, n = i - k * D_HID;
        Wt2[(size_t)n * D_HID + k] = f2bf(W2[i]);
    } else if (idx < S1 + S2 + S3) {
        int i = idx - S1 - S2;
        int k = i / D_OUT_, n = i - k * D_OUT_;
        Wt3[(size_t)n * D_HID + k] = f2bf(W3[i]);
    }
}

// ---------------- MFMA GEMM body: Cb[M][NOUT] bf16 = act(A)[M][K] @ Wt^T ----------
// FUSE: BN scale/shift computed per block from raw sums/sumsq into LDS.
// Layouts: A[m=lane&15][k=quad*8+j], B[k=quad*8+j][n=lane&15], C/D col=lane&15 row=quad*4+reg.
template<int K, int NOUT, int FUSE, int ABF16>
__device__ __forceinline__ void gemm_body(
        int bid, const void* __restrict__ Aptr, const unsigned short* __restrict__ Wt,
        unsigned short* __restrict__ Cb, int M,
        const float* __restrict__ sums, const float* __restrict__ sumsq,
        const float* __restrict__ gam, const float* __restrict__ bet, float invN) {
    constexpr int NT = NOUT / 16;
    constexpr int KS = K / 32;
    __shared__ float s_sc[FUSE ? K : 1];
    __shared__ float s_sh[FUSE ? K : 1];
    if (FUSE) {
        int t = threadIdx.x;
        if (t < K) {
            float mu  = sums[t] * invN;
            float var = sumsq[t] * invN - mu * mu;
            float sc  = gam[t] * rsqrtf(var + BN_EPS);
            s_sc[t] = sc;
            s_sh[t] = fmaf(-mu, sc, bet[t]);
        }
        __syncthreads();
    }
    int lane = threadIdx.x & 63;
    int wave = threadIdx.x >> 6;
    int col  = lane & 15;
    int quad = lane >> 4;
    int kq   = quad * 8;
    int row  = bid * 64 + wave * 16 + col;
    int rowc = min(row, M - 1);

    short8 afr[KS];
    if (ABF16) {
        const unsigned short* Ab = (const unsigned short*)Aptr;
        uint4 q[KS];
        #pragma unroll
        for (int i = 0; i < KS; ++i)
            q[i] = *(const uint4*)&Ab[(size_t)rowc * K + i * 32 + kq];
        __builtin_amdgcn_sched_barrier(0);   // all loads issued before converts
        #pragma unroll
        for (int i = 0; i < KS; ++i) {
            if (FUSE) {
                int kb = i * 32 + kq;
                float f0,f1,f2,f3,f4,f5,f6,f7;
                bf2_decode(q[i].x, f0, f1); bf2_decode(q[i].y, f2, f3);
                bf2_decode(q[i].z, f4, f5); bf2_decode(q[i].w, f6, f7);
                float4 sc0 = *(const float4*)&s_sc[kb];
                float4 sc1 = *(const float4*)&s_sc[kb + 4];
                float4 sh0 = *(const float4*)&s_sh[kb];
                float4 sh1 = *(const float4*)&s_sh[kb + 4];
                f0 = fmaxf(0.f, fmaf(f0, sc0.x, sh0.x));
                f1 = fmaxf(0.f, fmaf(f1, sc0.y, sh0.y));
                f2 = fmaxf(0.f, fmaf(f2, sc0.z, sh0.z));
                f3 = fmaxf(0.f, fmaf(f3, sc0.w, sh0.w));
                f4 = fmaxf(0.f, fmaf(f4, sc1.x, sh1.x));
                f5 = fmaxf(0.f, fmaf(f5, sc1.y, sh1.y));
                f6 = fmaxf(0.f, fmaf(f6, sc1.z, sh1.z));
                f7 = fmaxf(0.f, fmaf(f7, sc1.w, sh1.w));
                uint4 p;
                p.x = pack2bf(f0, f1); p.y = pack2bf(f2, f3);
                p.z = pack2bf(f4, f5); p.w = pack2bf(f6, f7);
                afr[i] = __builtin_bit_cast(short8, p);
            } else {
                afr[i] = __builtin_bit_cast(short8, q[i]);
            }
        }
    } else {
        const float* Af = (const float*)Aptr;
        float4 a0[KS], a1[KS];
        #pragma unroll
        for (int i = 0; i < KS; ++i) {
            a0[i] = *(const float4*)&Af[(size_t)rowc * K + i * 32 + kq];
            a1[i] = *(const float4*)&Af[(size_t)rowc * K + i * 32 + kq + 4];
        }
        __builtin_amdgcn_sched_barrier(0);   // all loads issued before converts
        #pragma unroll
        for (int i = 0; i < KS; ++i) {
            uint4 p;
            p.x = pack2bf(a0[i].x, a0[i].y); p.y = pack2bf(a0[i].z, a0[i].w);
            p.z = pack2bf(a1[i].x, a1[i].y); p.w = pack2bf(a1[i].z, a1[i].w);
            afr[i] = __builtin_bit_cast(short8, p);
        }
    }

    floatx4 acc[NT];
    #pragma unroll
    for (int nt = 0; nt < NT; ++nt) acc[nt] = (floatx4){0.f, 0.f, 0.f, 0.f};

    #pragma unroll
    for (int i = 0; i < KS; ++i) {
        #pragma unroll
        for (int nt = 0; nt < NT; ++nt) {
            short8 bfrag = *(const short8*)&Wt[(size_t)(nt * 16 + col) * K + i * 32 + kq];
            acc[nt] = __builtin_amdgcn_mfma_f32_16x16x32_bf16(afr[i], bfrag, acc[nt], 0, 0, 0);
        }
    }

    int obase = bid * 64 + wave * 16 + quad * 4;
    #pragma unroll
    for (int r = 0; r < 4; ++r) {
        int orow = obase + r;
        if (orow < M) {
            #pragma unroll
            for (int nt = 0; nt < NT; ++nt)
                Cb[(size_t)orow * NOUT + nt * 16 + col] = f2bf(acc[nt][r]);
        }
    }
}

template<int K, int NOUT, int FUSE, int ABF16>
__global__ __launch_bounds__(256, 3) void gemm_mfma_kernel(
        const void* __restrict__ Aptr, const unsigned short* __restrict__ Wt,
        unsigned short* __restrict__ Cb, int M,
        const float* __restrict__ sums, const float* __restrict__ sumsq,
        const float* __restrict__ gam, const float* __restrict__ bet, float invN) {
    gemm_body<K, NOUT, FUSE, ABF16>(blockIdx.x, Aptr, Wt, Cb, M, sums, sumsq, gam, bet, invN);
}

// ---- fused: blocks [0,GB) layer-1 GEMM, [GB,..) atomic-free CSR scatter ----
__global__ __launch_bounds__(256, 3) void gemm1_scatter_kernel(
        const float* __restrict__ x, const unsigned short* __restrict__ Wt1,
        unsigned short* __restrict__ Cb, int M, int GB,
        const int* __restrict__ src, const int* __restrict__ dst, int E,
        const int* __restrict__ rowstart, const int* __restrict__ rank,
        int* __restrict__ csr) {
    if ((int)blockIdx.x < GB) {
        gemm_body<D_IN, D_HID, 0, 0>(blockIdx.x, x, Wt1, Cb, M,
                                     nullptr, nullptr, nullptr, nullptr, 0.f);
    } else {
        int e = ((int)blockIdx.x - GB) * 256 + threadIdx.x;
        if (e < E) {
            int d = dst[e];
            csr[rowstart[d] + rank[e]] = src[e];   // no atomics
        }
    }
}

// ---------------- Aggregation (bf16 h, bf16 out, 4B CSR; w recomputed) -------------
// Barrier-free (r9 lesson). 8-deep unrolled gather for MLP.
template<int D>
__global__ __launch_bounds__(256) void agg_bf16_kernel(
        const unsigned short* __restrict__ h, const float* __restrict__ dinv,
        const int* __restrict__ rowstart, const int* __restrict__ csr,
        const float* __restrict__ bias,
        unsigned short* __restrict__ outb, int N) {
    constexpr int LPR = D / 8;           // lanes per row: 16 (D=128) / 8 (D=64)
    constexpr int RPB = 256 / LPR;       // rows per block: 16 / 32
    int lane = threadIdx.x & (LPR - 1);
    int r    = threadIdx.x / LPR;
    int v = blockIdx.x * RPB + r;
    if (v >= N) return;
    int c0 = lane * 8;
    const unsigned short* hc = h + c0;
    float dv = dinv[v];

    float acc[8];
    {   // self-loop term + bias
        float w = dv * dv;
        uint4 q = *(const uint4*)&hc[(size_t)v * D];
        float4 b0 = *(const float4*)&bias[c0];
        float4 b1 = *(const float4*)&bias[c0 + 4];
        acc[0]=b0.x; acc[1]=b0.y; acc[2]=b0.z; acc[3]=b0.w;
        acc[4]=b1.x; acc[5]=b1.y; acc[6]=b1.z; acc[7]=b1.w;
        accum8(acc, q, w);
    }

    int j  = rowstart[v];
    int j1 = rowstart[v + 1];
    for (; j + 8 <= j1; j += 8) {
        int   s[8]; float w[8]; uint4 q[8];
        #pragma unroll
        for (int i = 0; i < 8; ++i) s[i] = csr[j + i];
        #pragma unroll
        for (int i = 0; i < 8; ++i) q[i] = *(const uint4*)&hc[(size_t)s[i] * D];
        #pragma unroll
        for (int i = 0; i < 8; ++i) w[i] = dinv[s[i]] * dv;
        #pragma unroll
        for (int i = 0; i < 8; ++i) accum8(acc, q[i], w[i]);
    }
    for (; j + 4 <= j1; j += 4) {
        int s0 = csr[j],     s1 = csr[j + 1];
        int s2 = csr[j + 2], s3 = csr[j + 3];
        float w0 = dinv[s0] * dv, w1 = dinv[s1] * dv;
        float w2 = dinv[s2] * dv, w3 = dinv[s3] * dv;
        uint4 q0 = *(const uint4*)&hc[(size_t)s0 * D];
        uint4 q1 = *(const uint4*)&hc[(size_t)s1 * D];
        uint4 q2 = *(const uint4*)&hc[(size_t)s2 * D];
        uint4 q3 = *(const uint4*)&hc[(size_t)s3 * D];
        accum8(acc, q0, w0); accum8(acc, q1, w1);
        accum8(acc, q2, w2); accum8(acc, q3, w3);
    }
    for (; j < j1; ++j) {
        int s = csr[j];
        float w = dinv[s] * dv;
        uint4 q = *(const uint4*)&hc[(size_t)s * D];
        accum8(acc, q, w);
    }

    uint4 o;
    o.x = pack2bf(acc[0], acc[1]); o.y = pack2bf(acc[2], acc[3]);
    o.z = pack2bf(acc[4], acc[5]); o.w = pack2bf(acc[6], acc[7]);
    *(uint4*)&outb[(size_t)v * D + c0] = o;
}

// ---------------- BatchNorm stats (bf16 input, D=128) ----------------
__global__ void bn_stats_bf16_kernel(const unsigned short* __restrict__ x, int N,
                                     float* __restrict__ sums, float* __restrict__ sumsq) {
    __shared__ float ls0[256], ls1[256], lq0[256], lq1[256];
    int pr = threadIdx.x & 63;           // channel pair
    int rg = threadIdx.x >> 6;           // row group 0..3
    float s0=0.f, s1=0.f, q0=0.f, q1=0.f;
    for (int v = blockIdx.x * 4 + rg; v < N; v += gridDim.x * 4) {
        unsigned u = *(const unsigned*)&x[(size_t)v * 128 + pr * 2];
        float lo, hi; bf2_decode(u, lo, hi);
        s0 += lo; s1 += hi;
        q0 = fmaf(lo, lo, q0); q1 = fmaf(hi, hi, q1);
    }
    ls0[threadIdx.x]=s0; ls1[threadIdx.x]=s1; lq0[threadIdx.x]=q0; lq1[threadIdx.x]=q1;
    __syncthreads();
    if (threadIdx.x < 64) {
        int pp = threadIdx.x;
        float a0=0,a1=0,b0=0,b1=0;
        #pragma unroll
        for (int g = 0; g < 4; ++g) {
            a0 += ls0[g*64+pp]; a1 += ls1[g*64+pp];
            b0 += lq0[g*64+pp]; b1 += lq1[g*64+pp];
        }
        atomicAdd(&sums[pp*2],  a0); atomicAdd(&sums[pp*2+1],  a1);
        atomicAdd(&sumsq[pp*2], b0); atomicAdd(&sumsq[pp*2+1], b1);
    }
}

// ---------------- Global mean pool (bf16 input, D=64) ----------------
__global__ void pool_bf16_kernel(const unsigned short* __restrict__ x,
                                 const int* __restrict__ batch, int N,
                                 float* __restrict__ psum, int* __restrict__ pcnt) {
    __shared__ float ls[NGRAPH * 64];
    __shared__ int   lc[NGRAPH];
    for (int i = threadIdx.x; i < NGRAPH * 64; i += blockDim.x) ls[i] = 0.f;
    if (threadIdx.x < NGRAPH) lc[threadIdx.x] = 0;
    __syncthreads();
    int total = N * 32;
    for (int idx = blockIdx.x * blockDim.x + threadIdx.x; idx < total;
         idx += gridDim.x * blockDim.x) {
        int v = idx >> 5, cp = idx & 31;
        unsigned u = *(const unsigned*)&x[(size_t)v * 64 + cp * 2];
        float lo, hi; bf2_decode(u, lo, hi);
        int g = batch[v];
        atomicAdd(&ls[g * 64 + cp * 2],     lo);
        atomicAdd(&ls[g * 64 + cp * 2 + 1], hi);
        if (cp == 0) atomicAdd(&lc[g], 1);
    }
    __syncthreads();
    for (int i = threadIdx.x; i < NGRAPH * 64; i += blockDim.x) atomicAdd(&psum[i], ls[i]);
    if (threadIdx.x < NGRAPH) atomicAdd(&pcnt[threadIdx.x], lc[threadIdx.x]);
}

__global__ void pool_final_kernel(const float* __restrict__ psum, const int* __restrict__ pcnt,
                                  float* __restrict__ out) {
    int i = threadIdx.x;
    int g = i >> 6;
    float cnt = (float)max(pcnt[g], 1);
    out[i] = psum[i] / cnt;
}

// ---------------- launch ----------------
extern "C" void kernel_launch(void* const* d_in, const int* in_sizes, int n_in,
                              void* d_out, int out_size, void* d_ws, size_t ws_size,
                              hipStream_t stream) {
    const float* x   = (const float*)d_in[0];
    const int*   ei  = (const int*)d_in[1];
    const int*   bat = (const int*)d_in[2];
    const float* W1  = (const float*)d_in[3];
    const float* b1  = (const float*)d_in[4];
    const float* W2  = (const float*)d_in[5];
    const float* b2  = (const float*)d_in[6];
    const float* W3  = (const float*)d_in[7];
    const float* b3  = (const float*)d_in[8];
    const float* g1  = (const float*)d_in[9];
    const float* be1 = (const float*)d_in[10];
    const float* g2  = (const float*)d_in[11];
    const float* be2 = (const float*)d_in[12];
    float* out = (float*)d_out;

    int N = in_sizes[0] / D_IN;
    int E = in_sizes[1] / 2;
    const int* src = ei;
    const int* dst = ei + E;

    char* p = (char*)d_ws;
    auto alloc = [&](size_t bytes) { char* r = p; p += (bytes + 255) & ~(size_t)255; return r; };
    int NB = (N + SCAN_TPB * SCAN_VPT - 1) / (SCAN_TPB * SCAN_VPT);
    // ---- contiguous zero region: ONE memset covers deg + BN ping-pong + pool ----
    char*  zbase    = p;
    int*   deg      = (int*)  alloc((size_t)N * 4);
    float* sums1    = (float*)alloc(128 * 4);
    float* sumsq1   = (float*)alloc(128 * 4);
    float* sums2    = (float*)alloc(128 * 4);
    float* sumsq2   = (float*)alloc(128 * 4);
    float* psum     = (float*)alloc(NGRAPH * 64 * 4);
    int*   pcnt     = (int*)  alloc(NGRAPH * 4);
    size_t zspan    = (size_t)(p - zbase);
    // ---- rest of workspace ----
    int*   rowstart = (int*)  alloc((size_t)(N + 1) * 4);
    int*   rank     = (int*)  alloc((size_t)E * 4);
    float* dinv     = (float*)alloc((size_t)N * 4);
    int*   bsum     = (int*)  alloc((size_t)NB * 4);
    int*   bprefix  = (int*)  alloc((size_t)NB * 4);
    int*   csr      = (int*)  alloc((size_t)E * 4);
    unsigned short* hb16   = (unsigned short*)alloc((size_t)N * 128 * 2);  // GEMM out
    unsigned short* aggb16 = (unsigned short*)alloc((size_t)N * 128 * 2);  // agg out
    unsigned short* Wt1 = (unsigned short*)alloc((size_t)D_HID * D_IN * 2);
    unsigned short* Wt2 = (unsigned short*)alloc((size_t)D_HID * D_HID * 2);
    unsigned short* Wt3 = (unsigned short*)alloc((size_t)D_OUT_ * D_HID * 2);

    int tpb = 256;
    int ebl = (E + tpb - 1) / tpb;
    int gblocks = (N + 63) / 64;
    float invN = 1.0f / (float)N;
    int wtot = D_IN * D_HID + D_HID * D_HID + D_HID * D_OUT_;

    // ---- single memset + weight prep ----
    (void)hipMemsetAsync(zbase, 0, zspan, stream);
    wprep_all_kernel<<<(wtot + 255) / 256, 256, 0, stream>>>(W1, W2, W3, Wt1, Wt2, Wt3);

    // ---- CSR build ----
    count_rank_kernel<<<ebl, tpb, 0, stream>>>(dst, E, deg, rank);
    dinv_bsum_kernel<<<NB, SCAN_TPB, 0, stream>>>(deg, N, dinv, bsum);
    scan_bsum_kernel<<<1, SCAN_TPB, 0, stream>>>(bsum, NB, bprefix, rowstart, N, E);
    local_scan_kernel<<<NB, SCAN_TPB, 0, stream>>>(deg, N, bprefix, rowstart);

    // ---- Layer-1 GEMM fused with atomic-free CSR scatter ----
    gemm1_scatter_kernel<<<gblocks + ebl, 256, 0, stream>>>(
        x, Wt1, hb16, N, gblocks, src, dst, E, rowstart, rank, csr);

    // ---- Layer 1 ----
    agg_bf16_kernel<D_HID><<<(N + 15) / 16, 256, 0, stream>>>(
        hb16, dinv, rowstart, csr, b1, aggb16, N);
    bn_stats_bf16_kernel<<<256, 256, 0, stream>>>(aggb16, N, sums1, sumsq1);

    // ---- Layer 2 (BN-final + ReLU fused into GEMM) ----
    gemm_mfma_kernel<D_HID, D_HID, 1, 1><<<gblocks, 256, 0, stream>>>(
        aggb16, Wt2, hb16, N, sums1, sumsq1, g1, be1, invN);
    agg_bf16_kernel<D_HID><<<(N + 15) / 16, 256, 0, stream>>>(
        hb16, dinv, rowstart, csr, b2, aggb16, N);
    bn_stats_bf16_kernel<<<256, 256, 0, stream>>>(aggb16, N, sums2, sumsq2);

    // ---- Layer 3 ----
    gemm_mfma_kernel<D_HID, D_OUT_, 1, 1><<<gblocks, 256, 0, stream>>>(
        aggb16, Wt3, hb16, N, sums2, sumsq2, g2, be2, invN);
    agg_bf16_kernel<D_OUT_><<<(N + 31) / 32, 256, 0, stream>>>(
        hb16, dinv, rowstart, csr, b3, aggb16, N);

    // ---- Pool ----
    pool_bf16_kernel<<<256, 256, 0, stream>>>(aggb16, bat, N, psum, pcnt);
    pool_final_kernel<<<1, NGRAPH * 64, 0, stream>>>(psum, pcnt, out);
}